// Round 18
// baseline (16.584 us; speedup 1.0000x reference)
//
#include <hip/hip_runtime.h>

#define NQ 10
#define NR 16              // amplitudes per lane (2^4)

// r18 = r13 (11.44 us, verified) + batch-independent diagonal hoisted into a
// tiny precompute kernel.
//   psi_final = W . diag(e^{-i phi}) . W . psi_init   (r13-verified spectral form)
//   * phi(k) = sum over 30 X-string masks (r12-verified, full 10-bit form
//     M = (ML<<4)|MR) of +-theta/2 — depends only on w -> precomputed once
//     into d_ws[0..1023] as (cos phi, sin phi); d_ws[1024..1033] = layer-0
//     w sincos pairs. Main kernel loads 16 float2/lane (L2-resident).
//   * W psi_init product construction via j^-T      [r13-verified]
//   * W#2 butterfly + readout: r13 verbatim (DS lane_xor impls).

__device__ __forceinline__ float xf(int i) { return __int_as_float(i); }
__device__ __forceinline__ int   fx(float f) { return __float_as_int(f); }

template<int M>
__device__ __forceinline__ float lane_xor(float v, int a32) {
    if constexpr (M == 1)        // quad_perm [1,0,3,2]
        return xf(__builtin_amdgcn_update_dpp(fx(v), fx(v), 0xB1, 0xF, 0xF, true));
    else if constexpr (M == 2)   // quad_perm [2,3,0,1]
        return xf(__builtin_amdgcn_update_dpp(fx(v), fx(v), 0x4E, 0xF, 0xF, true));
    else if constexpr (M == 8)   // row_ror:8
        return xf(__builtin_amdgcn_update_dpp(fx(v), fx(v), 0x128, 0xF, 0xF, true));
    else if constexpr (M == 4)   // ds_swizzle bit-mode xor 4
        return xf(__builtin_amdgcn_ds_swizzle(fx(v), 0x101F));
    else if constexpr (M == 16)  // ds_swizzle bit-mode xor 16
        return xf(__builtin_amdgcn_ds_swizzle(fx(v), 0x401F));
    else                         // M == 32: bpermute
        return xf(__builtin_amdgcn_ds_bpermute(a32, fx(v)));
}

// ---- kernel 1: phase table (batch-independent) ----
__global__ __launch_bounds__(256) void phase_kernel(
    const float* __restrict__ w, float2* __restrict__ tbl)
{
    const int k = blockIdx.x * 256 + threadIdx.x;   // 0..1023
    // 30 X-string masks, full 10-bit form (layer1, layer2, layer3)
    const int M[30] = {512,256,128,64,32,16,8,4,2,1,
                       768,384,192,96,48,24,12,6,3,769,
                       640,320,160,80,40,20,10,5,770,385};
    float phi = 0.f;
    #pragma unroll
    for (int i = 0; i < 30; ++i) {
        const float h = 0.5f * w[10 + i];
        phi += (__builtin_popcount(k & M[i]) & 1) ? -h : h;
    }
    float sp, cp;
    __sincosf(phi, &sp, &cp);
    tbl[k] = make_float2(cp, sp);
    if (k < NQ) {                 // layer-0 weight sincos pairs
        float s, c;
        __sincosf(0.5f * w[k], &s, &c);
        tbl[1024 + k] = make_float2(c, s);
    }
}

// ---- kernel 2: main (one wave per batch element) ----
__global__ __launch_bounds__(256, 2) void vql_kernel(
    const float* __restrict__ x,     // (B, NQ)
    const float2* __restrict__ tbl,  // [1024] phases + [10] w0 pairs
    float* __restrict__ out,         // (B, NQ)
    int B)
{
    const int lane = threadIdx.x & 63;
    const int b = blockIdx.x * 4 + (threadIdx.x >> 6);
    if (b >= B) return;
    const int a32 = (lane ^ 32) << 2;

    // ---- issue phase-table loads EARLY (latency hides under init build) ----
    float2 E[NR];
    {
        const float2* tb = tbl + (lane << 4);
        #pragma unroll
        for (int r = 0; r < NR; ++r) E[r] = tb[r];
    }

    // ---- per-batch angles (vectorized) ----
    const float2* xr = reinterpret_cast<const float2*>(x + b * NQ);
    const float2 x01 = xr[0], x23 = xr[1], x45 = xr[2], x67 = xr[3], x89 = xr[4];
    const float xa[NQ] = {0.5f * x01.x, 0.5f * x01.y, 0.5f * x23.x, 0.5f * x23.y,
                          0.5f * x45.x, 0.5f * x45.y, 0.5f * x67.x, 0.5f * x67.y,
                          0.5f * x89.x, 0.5f * x89.y};

    // ---- per-qubit Walsh factors f'(t)=f(0)+-f(1) of RX(w0q)RY(xq)|0> ----
    float F0r[NQ], F0i[NQ], F1r[NQ], F1i[NQ];
    #pragma unroll
    for (int q = 0; q < NQ; ++q) {
        float sy, cy;
        __sincosf(xa[q], &sy, &cy);
        const float2 w0 = tbl[1024 + q];      // (c, s) of layer-0 weight
        const float v0r = w0.x * cy,  v0i = -w0.y * sy;
        const float v1r = w0.x * sy,  v1i = -w0.y * cy;
        F0r[q] = v0r + v1r;  F0i[q] = v0i + v1i;
        F1r[q] = v0r - v1r;  F1i[q] = v0i - v1i;
    }

    // ---- psi1 = W psi_init via j^-T bit formulas (r13-verified) ----
    const int L0 = lane & 1,        L1 = (lane >> 1) & 1, L2 = (lane >> 2) & 1;
    const int L3 = (lane >> 3) & 1, L4 = (lane >> 4) & 1, L5 = (lane >> 5) & 1;
    const int PL1 = L0 ^ L1, PL2 = PL1 ^ L2, PL3 = PL2 ^ L3, PL4 = PL3 ^ L4;
    const int g[7] = {PL4, PL4 ^ L5, PL3 ^ L5, PL2 ^ L5, PL1 ^ L5, L0 ^ L5, L5};
    #define SR_(q,bit) ((bit) ? F1r[q] : F0r[q])
    #define SI_(q,bit) ((bit) ? F1i[q] : F0i[q])

    float A_r[2], A_i[2];                 // prod q=0..6, for rp4 = 0/1
    #pragma unroll
    for (int t = 0; t < 2; ++t) {
        float ar = SR_(0, g[0] ^ t), ai = SI_(0, g[0] ^ t);
        #pragma unroll
        for (int q = 1; q < 7; ++q) {
            const float br = SR_(q, g[q] ^ t), bi = SI_(q, g[q] ^ t);
            const float nr = ar * br - ai * bi;
            const float ni = ar * bi + ai * br;
            ar = nr; ai = ni;
        }
        A_r[t] = ar * (1.0f / 1024.0f);   // fold W.W normalization
        A_i[t] = ai * (1.0f / 1024.0f);
    }
    float Gr[2][2], Gi[2][2];             // u8[t2]*u9[t1]
    #pragma unroll
    for (int t2 = 0; t2 < 2; ++t2)
        #pragma unroll
        for (int t1 = 0; t1 < 2; ++t1) {
            const float ar = SR_(8, t2 ^ L5), ai = SI_(8, t2 ^ L5);
            const float br = SR_(9, t1 ^ L5), bi = SI_(9, t1 ^ L5);
            Gr[t2][t1] = ar * br - ai * bi;
            Gi[t2][t1] = ar * bi + ai * br;
        }
    float Br_[2][2][2], Bi_[2][2][2];     // u7[t3]*G[t2][t1]
    #pragma unroll
    for (int t3 = 0; t3 < 2; ++t3)
        #pragma unroll
        for (int t2 = 0; t2 < 2; ++t2)
            #pragma unroll
            for (int t1 = 0; t1 < 2; ++t1) {
                const float ar = SR_(7, t3 ^ L5), ai = SI_(7, t3 ^ L5);
                Br_[t3][t2][t1] = ar * Gr[t2][t1] - ai * Gi[t2][t1];
                Bi_[t3][t2][t1] = ar * Gi[t2][t1] + ai * Gr[t2][t1];
            }
    float re[NR], im[NR];
    #pragma unroll
    for (int r = 0; r < NR; ++r) {
        const int r0 = r & 1, r1 = (r >> 1) & 1, r2 = (r >> 2) & 1, r3 = (r >> 3) & 1;
        const int p1 = r0, p2 = r0 ^ r1, p3 = p2 ^ r2, p4 = p3 ^ r3;
        const float br = Br_[p3][p2][p1], bi = Bi_[p3][p2][p1];
        re[r] = A_r[p4] * br - A_i[p4] * bi;
        im[r] = A_r[p4] * bi + A_i[p4] * br;
    }
    #undef SR_
    #undef SI_

    // ---- apply precomputed diagonal e^{-i phi} ----
    #pragma unroll
    for (int r = 0; r < NR; ++r) {
        const float cp = E[r].x, sp = E[r].y;
        const float nr = re[r] * cp + im[r] * sp;
        const float ni = im[r] * cp - re[r] * sp;
        re[r] = nr; im[r] = ni;
    }

    // ---- W#2: 10-level Walsh butterfly (r13 verbatim) ----
    #pragma unroll
    for (int bset = 0; bset < 4; ++bset) {      // reg levels (VALU only)
        const int bb = 1 << bset;
        #pragma unroll
        for (int r = 0; r < NR; ++r) {
            if (!(r & bb)) {
                float u = re[r], v = re[r | bb];
                re[r] = u + v;  re[r | bb] = u - v;
                u = im[r]; v = im[r | bb];
                im[r] = u + v;  im[r | bb] = u - v;
            }
        }
    }
    {
        const float sgA = (lane &  1) ? -1.f : 1.f;
        const float sgB = (lane &  2) ? -1.f : 1.f;
        const float sgC = (lane &  4) ? -1.f : 1.f;
        const float sgD = (lane &  8) ? -1.f : 1.f;
        const float sgE = (lane & 16) ? -1.f : 1.f;
        const float sgF = (lane & 32) ? -1.f : 1.f;
        #pragma unroll
        for (int r = 0; r < NR; ++r) {
            float p;
            p = lane_xor< 1>(re[r], a32); re[r] = fmaf(sgA, re[r], p);
            p = lane_xor< 1>(im[r], a32); im[r] = fmaf(sgA, im[r], p);
            p = lane_xor< 2>(re[r], a32); re[r] = fmaf(sgB, re[r], p);
            p = lane_xor< 2>(im[r], a32); im[r] = fmaf(sgB, im[r], p);
            p = lane_xor< 4>(re[r], a32); re[r] = fmaf(sgC, re[r], p);
            p = lane_xor< 4>(im[r], a32); im[r] = fmaf(sgC, im[r], p);
            p = lane_xor< 8>(re[r], a32); re[r] = fmaf(sgD, re[r], p);
            p = lane_xor< 8>(im[r], a32); im[r] = fmaf(sgD, im[r], p);
            p = lane_xor<16>(re[r], a32); re[r] = fmaf(sgE, re[r], p);
            p = lane_xor<16>(im[r], a32); im[r] = fmaf(sgE, im[r], p);
            p = lane_xor<32>(re[r], a32); re[r] = fmaf(sgF, re[r], p);
            p = lane_xor<32>(im[r], a32); im[r] = fmaf(sgF, im[r], p);
        }
    }

    // ---- readout: parity-mask observables (r12/r13 verbatim) ----
    float W[NR];
    #pragma unroll
    for (int r = 0; r < NR; ++r) W[r] = re[r] * re[r] + im[r] * im[r];
    #pragma unroll
    for (int bset = 0; bset < 4; ++bset) {
        const int bb = 1 << bset;
        #pragma unroll
        for (int r = 0; r < NR; ++r) {
            if (!(r & bb)) {
                const float u = W[r], v = W[r | bb];
                W[r] = u + v;  W[r | bb] = u - v;
            }
        }
    }
    const float sg44 = (__builtin_popcount(lane & 44) & 1) ? -1.f : 1.f;
    const float sg26 = (__builtin_popcount(lane & 26) & 1) ? -1.f : 1.f;
    const float sg13 = (__builtin_popcount(lane & 13) & 1) ? -1.f : 1.f;
    const float sg38 = (__builtin_popcount(lane & 38) & 1) ? -1.f : 1.f;
    const float sg51 = (__builtin_popcount(lane & 51) & 1) ? -1.f : 1.f;
    const float sg25 = (__builtin_popcount(lane & 25) & 1) ? -1.f : 1.f;
    const float sg12 = (__builtin_popcount(lane & 12) & 1) ? -1.f : 1.f;

    float z[NQ];
    z[0] = sg44 * W[12];
    z[1] = sg26 * W[10];
    z[2] = sg13 * W[ 5];
    z[3] = sg38 * W[10];
    z[4] = sg51 * W[ 5];
    z[5] = sg25 * W[10];
    z[6] = sg12 * W[13];
    z[7] = sg38 * W[ 6];
    z[8] = sg51 * W[ 3];
    z[9] = sg25 * W[ 9];

    #pragma unroll
    for (int q = 0; q < NQ; ++q) {
        z[q] += lane_xor<1>(z[q], a32);
        z[q] += lane_xor<2>(z[q], a32);
        z[q] += lane_xor<4>(z[q], a32);
        z[q] += lane_xor<8>(z[q], a32);
        z[q] += lane_xor<16>(z[q], a32);
        z[q] += lane_xor<32>(z[q], a32);
    }
    if (lane == 0) {
        #pragma unroll
        for (int q = 0; q < NQ; ++q) out[b * NQ + q] = z[q];
    }
}

extern "C" void kernel_launch(void* const* d_in, const int* in_sizes, int n_in,
                              void* d_out, int out_size, void* d_ws, size_t ws_size,
                              hipStream_t stream) {
    const float* x = (const float*)d_in[0];        // (BATCH, NQ) fp32
    const float* w = (const float*)d_in[1];        // (NDEPTH, NQ) fp32
    float* out = (float*)d_out;                    // (BATCH, NQ) fp32
    float2* tbl = (float2*)d_ws;                   // 1034 float2 = 8272 B
    const int B = in_sizes[0] / NQ;
    phase_kernel<<<4, 256, 0, stream>>>(w, tbl);
    vql_kernel<<<(B + 3) / 4, 256, 0, stream>>>(x, tbl, out, B);
}

// Round 19
// 11.050 us; speedup vs baseline: 1.5008x; 1.5008x over previous
//
#include <hip/hip_runtime.h>

#define NQ 10
#define NR 16              // amplitudes per lane (2^4)

// One WAVE per batch element: 64 lanes x 16 complex amps = 1024 amplitudes.
// Flat index k = lane*16 + r; bit c of k: c>=4 -> lane bit (c-4), c<4 -> reg bit c.
// r19 = r13 (11.44 us, best verified) + packed output stores + exact grid.
//   psi_final = W . diag(e^{-i phi}) . W . psi_init   (spectral form)
//   * W psi_init built directly (j^-T product construction)   [r13-verified]
//   * phi via 16-pt WHT of lane-signed coefficients           [r13-verified]
//   * W#2 butterfly + readout parity masks                    [r12/r13-verified]

__device__ __forceinline__ float xf(int i) { return __int_as_float(i); }
__device__ __forceinline__ int   fx(float f) { return __float_as_int(f); }

template<int M>
__device__ __forceinline__ float lane_xor(float v, int a32) {
    if constexpr (M == 1)        // quad_perm [1,0,3,2]
        return xf(__builtin_amdgcn_update_dpp(fx(v), fx(v), 0xB1, 0xF, 0xF, true));
    else if constexpr (M == 2)   // quad_perm [2,3,0,1]
        return xf(__builtin_amdgcn_update_dpp(fx(v), fx(v), 0x4E, 0xF, 0xF, true));
    else if constexpr (M == 8)   // row_ror:8
        return xf(__builtin_amdgcn_update_dpp(fx(v), fx(v), 0x128, 0xF, 0xF, true));
    else if constexpr (M == 4)   // ds_swizzle bit-mode xor 4
        return xf(__builtin_amdgcn_ds_swizzle(fx(v), 0x101F));
    else if constexpr (M == 16)  // ds_swizzle bit-mode xor 16
        return xf(__builtin_amdgcn_ds_swizzle(fx(v), 0x401F));
    else                         // M == 32: bpermute
        return xf(__builtin_amdgcn_ds_bpermute(a32, fx(v)));
}

__global__ __launch_bounds__(256, 2) void vql_kernel(
    const float* __restrict__ x,     // (B, NQ)
    const float* __restrict__ w,     // (NDEPTH, NQ)
    float* __restrict__ out)         // (B, NQ)
{
    const int lane = threadIdx.x & 63;
    const int b = blockIdx.x * 4 + (threadIdx.x >> 6);
    const int a32 = (lane ^ 32) << 2;

    // ---- per-batch angles (vectorized) ----
    const float2* xr = reinterpret_cast<const float2*>(x + b * NQ);
    const float2 x01 = xr[0], x23 = xr[1], x45 = xr[2], x67 = xr[3], x89 = xr[4];
    const float xa[NQ] = {0.5f * x01.x, 0.5f * x01.y, 0.5f * x23.x, 0.5f * x23.y,
                          0.5f * x45.x, 0.5f * x45.y, 0.5f * x67.x, 0.5f * x67.y,
                          0.5f * x89.x, 0.5f * x89.y};

    // ---- per-qubit Walsh factors of RX(w0q)RY(xq)|0>:  f'(t) = f(0) +- f(1) ----
    float F0r[NQ], F0i[NQ], F1r[NQ], F1i[NQ];
    #pragma unroll
    for (int q = 0; q < NQ; ++q) {
        float sy, cy, s, c;
        __sincosf(xa[q], &sy, &cy);
        __sincosf(0.5f * w[q], &s, &c);   // layer-0 weights
        const float v0r = c * cy,  v0i = -s * sy;
        const float v1r = c * sy,  v1i = -s * cy;
        F0r[q] = v0r + v1r;  F0i[q] = v0i + v1i;
        F1r[q] = v0r - v1r;  F1i[q] = v0i - v1i;
    }

    // ---- psi1 = W psi_init via j^-T bit formulas (r13-verified) ----
    const int L0 = lane & 1,        L1 = (lane >> 1) & 1, L2 = (lane >> 2) & 1;
    const int L3 = (lane >> 3) & 1, L4 = (lane >> 4) & 1, L5 = (lane >> 5) & 1;
    const int PL1 = L0 ^ L1, PL2 = PL1 ^ L2, PL3 = PL2 ^ L3, PL4 = PL3 ^ L4;
    const int g[7] = {PL4, PL4 ^ L5, PL3 ^ L5, PL2 ^ L5, PL1 ^ L5, L0 ^ L5, L5};
    #define SR_(q,bit) ((bit) ? F1r[q] : F0r[q])
    #define SI_(q,bit) ((bit) ? F1i[q] : F0i[q])

    float A_r[2], A_i[2];                 // prod q=0..6, for rp4 = 0/1
    #pragma unroll
    for (int t = 0; t < 2; ++t) {
        float ar = SR_(0, g[0] ^ t), ai = SI_(0, g[0] ^ t);
        #pragma unroll
        for (int q = 1; q < 7; ++q) {
            const float br = SR_(q, g[q] ^ t), bi = SI_(q, g[q] ^ t);
            const float nr = ar * br - ai * bi;
            const float ni = ar * bi + ai * br;
            ar = nr; ai = ni;
        }
        A_r[t] = ar * (1.0f / 1024.0f);   // fold W.W normalization
        A_i[t] = ai * (1.0f / 1024.0f);
    }
    float Gr[2][2], Gi[2][2];             // u8[t2]*u9[t1]
    #pragma unroll
    for (int t2 = 0; t2 < 2; ++t2)
        #pragma unroll
        for (int t1 = 0; t1 < 2; ++t1) {
            const float ar = SR_(8, t2 ^ L5), ai = SI_(8, t2 ^ L5);
            const float br = SR_(9, t1 ^ L5), bi = SI_(9, t1 ^ L5);
            Gr[t2][t1] = ar * br - ai * bi;
            Gi[t2][t1] = ar * bi + ai * br;
        }
    float Br_[2][2][2], Bi_[2][2][2];     // u7[t3]*G[t2][t1]
    #pragma unroll
    for (int t3 = 0; t3 < 2; ++t3)
        #pragma unroll
        for (int t2 = 0; t2 < 2; ++t2)
            #pragma unroll
            for (int t1 = 0; t1 < 2; ++t1) {
                const float ar = SR_(7, t3 ^ L5), ai = SI_(7, t3 ^ L5);
                Br_[t3][t2][t1] = ar * Gr[t2][t1] - ai * Gi[t2][t1];
                Bi_[t3][t2][t1] = ar * Gi[t2][t1] + ai * Gr[t2][t1];
            }
    float re[NR], im[NR];
    #pragma unroll
    for (int r = 0; r < NR; ++r) {
        const int r0 = r & 1, r1 = (r >> 1) & 1, r2 = (r >> 2) & 1, r3 = (r >> 3) & 1;
        const int p1 = r0, p2 = r0 ^ r1, p3 = p2 ^ r2, p4 = p3 ^ r3;
        const float br = Br_[p3][p2][p1], bi = Bi_[p3][p2][p1];
        re[r] = A_r[p4] * br - A_i[p4] * bi;
        im[r] = A_r[p4] * bi + A_i[p4] * br;
    }
    #undef SR_
    #undef SI_

    // ---- diagonal phases: phi[r] via 16-pt WHT of lane-signed coeffs ----
    float h1[NQ], h2[NQ], h3[NQ];
    #pragma unroll
    for (int q = 0; q < NQ; ++q) {
        h1[q] = 0.5f * w[NQ + q];
        h2[q] = 0.5f * w[2 * NQ + q];
        h3[q] = 0.5f * w[3 * NQ + q];
    }
    #define SG_(M) ((__builtin_popcount(lane & (M)) & 1) ? -1.f : 1.f)
    const float s1 = SG_(1),  s2 = SG_(2),  s3 = SG_(3),  s4 = SG_(4),  s5 = SG_(5);
    const float s6 = SG_(6),  s8 = SG_(8),  s10 = SG_(10), s12 = SG_(12);
    const float s16 = SG_(16), s20 = SG_(20), s24 = SG_(24), s32 = SG_(32);
    const float s40 = SG_(40), s48 = SG_(48);
    #undef SG_

    float C[NR];
    C[0]  = s32 * h1[0] + s16 * h1[1] + s8 * h1[2] + s4 * h1[3] + s2 * h1[4] + s1 * h1[5]
          + s48 * h2[0] + s24 * h2[1] + s12 * h2[2] + s6 * h2[3] + s3 * h2[4]
          + s40 * h3[0] + s20 * h3[1] + s10 * h3[2] + s5 * h3[3];
    C[8]  = h1[6] + s1 * h2[5] + s2 * h3[4];
    C[4]  = h1[7] + s1 * h3[5];
    C[2]  = h1[8] + s48 * h3[8];
    C[1]  = h1[9] + s48 * h2[9] + s24 * h3[9];
    C[12] = h2[6];
    C[6]  = h2[7];
    C[3]  = h2[8];
    C[10] = h3[6];
    C[5]  = h3[7];
    C[7] = 0.f; C[9] = 0.f; C[11] = 0.f; C[13] = 0.f; C[14] = 0.f; C[15] = 0.f;

    #pragma unroll
    for (int bset = 0; bset < 4; ++bset) {      // 16-pt WHT: C -> phi
        const int bb = 1 << bset;
        #pragma unroll
        for (int r = 0; r < NR; ++r) {
            if (!(r & bb)) {
                const float u = C[r], v = C[r | bb];
                C[r] = u + v;  C[r | bb] = u - v;
            }
        }
    }
    // apply e^{-i phi}
    #pragma unroll
    for (int r = 0; r < NR; ++r) {
        float sp, cp;
        __sincosf(C[r], &sp, &cp);
        const float nr = re[r] * cp + im[r] * sp;
        const float ni = im[r] * cp - re[r] * sp;
        re[r] = nr; im[r] = ni;
    }

    // ---- W#2: 10-level Walsh butterfly (r13 verbatim) ----
    #pragma unroll
    for (int bset = 0; bset < 4; ++bset) {      // reg levels (VALU only)
        const int bb = 1 << bset;
        #pragma unroll
        for (int r = 0; r < NR; ++r) {
            if (!(r & bb)) {
                float u = re[r], v = re[r | bb];
                re[r] = u + v;  re[r | bb] = u - v;
                u = im[r]; v = im[r | bb];
                im[r] = u + v;  im[r | bb] = u - v;
            }
        }
    }
    {
        const float sgA = (lane &  1) ? -1.f : 1.f;
        const float sgB = (lane &  2) ? -1.f : 1.f;
        const float sgC = (lane &  4) ? -1.f : 1.f;
        const float sgD = (lane &  8) ? -1.f : 1.f;
        const float sgE = (lane & 16) ? -1.f : 1.f;
        const float sgF = (lane & 32) ? -1.f : 1.f;
        #pragma unroll
        for (int r = 0; r < NR; ++r) {
            float p;
            p = lane_xor< 1>(re[r], a32); re[r] = fmaf(sgA, re[r], p);
            p = lane_xor< 1>(im[r], a32); im[r] = fmaf(sgA, im[r], p);
            p = lane_xor< 2>(re[r], a32); re[r] = fmaf(sgB, re[r], p);
            p = lane_xor< 2>(im[r], a32); im[r] = fmaf(sgB, im[r], p);
            p = lane_xor< 4>(re[r], a32); re[r] = fmaf(sgC, re[r], p);
            p = lane_xor< 4>(im[r], a32); im[r] = fmaf(sgC, im[r], p);
            p = lane_xor< 8>(re[r], a32); re[r] = fmaf(sgD, re[r], p);
            p = lane_xor< 8>(im[r], a32); im[r] = fmaf(sgD, im[r], p);
            p = lane_xor<16>(re[r], a32); re[r] = fmaf(sgE, re[r], p);
            p = lane_xor<16>(im[r], a32); im[r] = fmaf(sgE, im[r], p);
            p = lane_xor<32>(re[r], a32); re[r] = fmaf(sgF, re[r], p);
            p = lane_xor<32>(im[r], a32); im[r] = fmaf(sgF, im[r], p);
        }
    }

    // ---- readout: parity-mask observables (r12/r13 verbatim) ----
    float W[NR];
    #pragma unroll
    for (int r = 0; r < NR; ++r) W[r] = re[r] * re[r] + im[r] * im[r];
    #pragma unroll
    for (int bset = 0; bset < 4; ++bset) {
        const int bb = 1 << bset;
        #pragma unroll
        for (int r = 0; r < NR; ++r) {
            if (!(r & bb)) {
                const float u = W[r], v = W[r | bb];
                W[r] = u + v;  W[r | bb] = u - v;
            }
        }
    }
    const float sg44 = (__builtin_popcount(lane & 44) & 1) ? -1.f : 1.f;
    const float sg26 = (__builtin_popcount(lane & 26) & 1) ? -1.f : 1.f;
    const float sg13 = (__builtin_popcount(lane & 13) & 1) ? -1.f : 1.f;
    const float sg38 = (__builtin_popcount(lane & 38) & 1) ? -1.f : 1.f;
    const float sg51 = (__builtin_popcount(lane & 51) & 1) ? -1.f : 1.f;
    const float sg25 = (__builtin_popcount(lane & 25) & 1) ? -1.f : 1.f;
    const float sg12 = (__builtin_popcount(lane & 12) & 1) ? -1.f : 1.f;

    float z[NQ];
    z[0] = sg44 * W[12];
    z[1] = sg26 * W[10];
    z[2] = sg13 * W[ 5];
    z[3] = sg38 * W[10];
    z[4] = sg51 * W[ 5];
    z[5] = sg25 * W[10];
    z[6] = sg12 * W[13];
    z[7] = sg38 * W[ 6];
    z[8] = sg51 * W[ 3];
    z[9] = sg25 * W[ 9];

    #pragma unroll
    for (int q = 0; q < NQ; ++q) {
        z[q] += lane_xor<1>(z[q], a32);
        z[q] += lane_xor<2>(z[q], a32);
        z[q] += lane_xor<4>(z[q], a32);
        z[q] += lane_xor<8>(z[q], a32);
        z[q] += lane_xor<16>(z[q], a32);
        z[q] += lane_xor<32>(z[q], a32);
    }
    if (lane == 0) {
        // packed output: 10 floats = float4 + float4 + float2 (out 8B-aligned;
        // b*NQ*4 % 16 == 0 or 8 — use float2 stores to be alignment-safe)
        float2* op = reinterpret_cast<float2*>(out + b * NQ);
        op[0] = make_float2(z[0], z[1]);
        op[1] = make_float2(z[2], z[3]);
        op[2] = make_float2(z[4], z[5]);
        op[3] = make_float2(z[6], z[7]);
        op[4] = make_float2(z[8], z[9]);
    }
}

extern "C" void kernel_launch(void* const* d_in, const int* in_sizes, int n_in,
                              void* d_out, int out_size, void* d_ws, size_t ws_size,
                              hipStream_t stream) {
    const float* x = (const float*)d_in[0];        // (BATCH, NQ) fp32
    const float* w = (const float*)d_in[1];        // (NDEPTH, NQ) fp32
    float* out = (float*)d_out;                    // (BATCH, NQ) fp32
    const int B = in_sizes[0] / NQ;                // 2048 (divisible by 4)
    vql_kernel<<<B / 4, 256, 0, stream>>>(x, w, out);
}